// Round 1
// baseline (483.849 us; speedup 1.0000x reference)
//
#include <hip/hip_runtime.h>
#include <math.h>

#define NB 16
#define NC 256
#define NN 1024
#define GN_EPS 1e-5f

// ---------------------------------------------------------------------------
// Kernel 1: GroupNorm statistics. One block per (b, g); group = 8 ch x 1024 px
// = 8192 contiguous floats. Writes (mean, rstd) per group.
// ---------------------------------------------------------------------------
__global__ __launch_bounds__(256) void gn_stats_kernel(
    const float* __restrict__ x, float2* __restrict__ stats)
{
    const int bg = blockIdx.x;          // b*32 + g
    const int t  = threadIdx.x;
    const size_t base = (size_t)bg * 8192;
    float s = 0.f, ss = 0.f;
#pragma unroll
    for (int i = 0; i < 32; ++i) {
        float v = x[base + t + i * 256];
        s += v; ss += v * v;
    }
#pragma unroll
    for (int off = 32; off > 0; off >>= 1) {
        s  += __shfl_down(s, off);
        ss += __shfl_down(ss, off);
    }
    __shared__ float red[8];
    const int wid = t >> 6;
    if ((t & 63) == 0) { red[wid] = s; red[4 + wid] = ss; }
    __syncthreads();
    if (t == 0) {
        float sa = red[0] + red[1] + red[2] + red[3];
        float sb = red[4] + red[5] + red[6] + red[7];
        float mean = sa * (1.0f / 8192.0f);
        float var  = sb * (1.0f / 8192.0f) - mean * mean;
        stats[bg] = make_float2(mean, 1.0f / sqrtf(var + GN_EPS));
    }
}

// ---------------------------------------------------------------------------
// Kernel 2/4: batched GEMM  Y[b,o,n] = sum_c W[o,c] * X[b,c,n] + bias[o]
// GNORM: X-tile load applies (x-mean)*rstd*gamma+beta on the fly.
// RESIDUAL: Y += R at same index.
// Tiles: 64(o) x 64(n), K stepped by 64. 256 thr, 4x4 microtile/thread.
// LDS layouts padded to 68 floats so inner loops are float4 (b128) reads.
// ---------------------------------------------------------------------------
template<bool GNORM, bool RESIDUAL>
__global__ __launch_bounds__(256) void gemm_kernel(
    const float* __restrict__ W, const float* __restrict__ bias,
    const float* __restrict__ X, const float2* __restrict__ stats,
    const float* __restrict__ gamma, const float* __restrict__ beta,
    const float* __restrict__ R, float* __restrict__ Y,
    int M, int K)
{
    const int b  = blockIdx.z;
    const int ot = blockIdx.y;
    const int nt = blockIdx.x;
    const int t  = threadIdx.x;
    const int tx = t & 15, ty = t >> 4;
    __shared__ float Wst[64][68];   // [k][o]  (transposed on store)
    __shared__ float Xs[64][68];    // [k][n]
    float acc[4][4] = {};
    const float* Xb = X + (size_t)b * K * NN;

    for (int kk = 0; kk < K; kk += 64) {
#pragma unroll
        for (int i = 0; i < 16; ++i) {
            int idx = t + i * 256;
            int row = idx >> 6, col = idx & 63;
            Wst[col][row] = W[(size_t)(ot * 64 + row) * K + kk + col];
            float xv = Xb[(size_t)(kk + row) * NN + nt * 64 + col];
            if (GNORM) {
                int c = kk + row;
                float2 st = stats[b * 32 + (c >> 3)];
                xv = (xv - st.x) * st.y * gamma[c] + beta[c];
            }
            Xs[row][col] = xv;
        }
        __syncthreads();
#pragma unroll 8
        for (int k = 0; k < 64; ++k) {
            float4 a  = *(const float4*)&Wst[k][ty * 4];
            float4 bb = *(const float4*)&Xs[k][tx * 4];
            float av[4] = {a.x, a.y, a.z, a.w};
            float bv[4] = {bb.x, bb.y, bb.z, bb.w};
#pragma unroll
            for (int i = 0; i < 4; ++i)
#pragma unroll
                for (int j = 0; j < 4; ++j)
                    acc[i][j] += av[i] * bv[j];
        }
        __syncthreads();
    }
    const int o0 = ot * 64 + ty * 4;
    const int n0 = nt * 64 + tx * 4;
#pragma unroll
    for (int i = 0; i < 4; ++i) {
        const int o = o0 + i;
        const float bi = bias[o];
        const size_t rowoff = ((size_t)b * M + o) * NN + n0;
#pragma unroll
        for (int j = 0; j < 4; ++j) {
            float val = acc[i][j] + bi;
            if (RESIDUAL) val += R[rowoff + j];
            Y[rowoff + j] = val;
        }
    }
}

// ---------------------------------------------------------------------------
// Kernel 3: flash attention. One block per (b, head, 64-query tile).
// qkv layout: [B][3*256][1024]; q row d contiguous in n.
// s[n,m] = 0.125 * sum_d q[d,n] k[d,m]; online softmax over m;
// o[d,n] = sum_m p[n,m] v[d,m].
// Thread (ty,tx): scores n=ty*4+i, m=tx*4+j; output n=ty*4+i, d=tx*4+j
// (same n ownership -> softmax stats stay in-thread).
// ---------------------------------------------------------------------------
__global__ __launch_bounds__(256) void attn_kernel(
    const float* __restrict__ qkv, float* __restrict__ ao)
{
    const int nt = blockIdx.x;
    const int hh = blockIdx.y;
    const int b  = blockIdx.z;
    const int t  = threadIdx.x;
    const int tx = t & 15, ty = t >> 4;
    __shared__ float Qs [64][68];   // [d][n]
    __shared__ float Ks [64][68];   // [d][m]
    __shared__ float VsT[64][68];   // [m][d] (transposed on store)
    __shared__ float PsT[64][68];   // [m][n] (transposed on store)

    const float* qb = qkv + ((size_t)b * 768 + hh * 64) * NN;
    const float* kb = qb + 256 * NN;
    const float* vb = qb + 512 * NN;

#pragma unroll
    for (int i = 0; i < 16; ++i) {
        int idx = t + i * 256;
        int row = idx >> 6, col = idx & 63;
        Qs[row][col] = qb[(size_t)row * NN + nt * 64 + col];
    }

    float m_run[4], l_run[4], o_acc[4][4] = {};
#pragma unroll
    for (int i = 0; i < 4; ++i) { m_run[i] = -1e30f; l_run[i] = 0.f; }

    for (int mt = 0; mt < 16; ++mt) {
#pragma unroll
        for (int i = 0; i < 16; ++i) {
            int idx = t + i * 256;
            int row = idx >> 6, col = idx & 63;
            Ks[row][col]  = kb[(size_t)row * NN + mt * 64 + col];
            VsT[col][row] = vb[(size_t)row * NN + mt * 64 + col];
        }
        __syncthreads();

        // QK^T
        float sacc[4][4] = {};
#pragma unroll 8
        for (int d = 0; d < 64; ++d) {
            float4 a  = *(const float4*)&Qs[d][ty * 4];
            float4 bb = *(const float4*)&Ks[d][tx * 4];
            float av[4] = {a.x, a.y, a.z, a.w};
            float bv[4] = {bb.x, bb.y, bb.z, bb.w};
#pragma unroll
            for (int i = 0; i < 4; ++i)
#pragma unroll
                for (int j = 0; j < 4; ++j)
                    sacc[i][j] += av[i] * bv[j];
        }
#pragma unroll
        for (int i = 0; i < 4; ++i)
#pragma unroll
            for (int j = 0; j < 4; ++j)
                sacc[i][j] *= 0.125f;

        // online softmax (row reduce over m across 16 lanes, same-wave)
        float rmax[4];
#pragma unroll
        for (int i = 0; i < 4; ++i)
            rmax[i] = fmaxf(fmaxf(sacc[i][0], sacc[i][1]),
                            fmaxf(sacc[i][2], sacc[i][3]));
#pragma unroll
        for (int off = 1; off < 16; off <<= 1)
#pragma unroll
            for (int i = 0; i < 4; ++i)
                rmax[i] = fmaxf(rmax[i], __shfl_xor(rmax[i], off));

        float fac[4], rsum[4];
#pragma unroll
        for (int i = 0; i < 4; ++i) {
            float nm = fmaxf(m_run[i], rmax[i]);
            fac[i] = __expf(m_run[i] - nm);
            m_run[i] = nm;
            float rs = 0.f;
#pragma unroll
            for (int j = 0; j < 4; ++j) {
                sacc[i][j] = __expf(sacc[i][j] - nm);
                rs += sacc[i][j];
            }
            rsum[i] = rs;
        }
#pragma unroll
        for (int off = 1; off < 16; off <<= 1)
#pragma unroll
            for (int i = 0; i < 4; ++i)
                rsum[i] += __shfl_xor(rsum[i], off);
#pragma unroll
        for (int i = 0; i < 4; ++i) l_run[i] = l_run[i] * fac[i] + rsum[i];

#pragma unroll
        for (int i = 0; i < 4; ++i)
#pragma unroll
            for (int j = 0; j < 4; ++j)
                PsT[tx * 4 + j][ty * 4 + i] = sacc[i][j];
#pragma unroll
        for (int i = 0; i < 4; ++i)
#pragma unroll
            for (int j = 0; j < 4; ++j)
                o_acc[i][j] *= fac[i];
        __syncthreads();

        // PV: o[n=ty*4+i][d=tx*4+j] += sum_m PsT[m][n] * VsT[m][d]
#pragma unroll 8
        for (int m = 0; m < 64; ++m) {
            float4 pv = *(const float4*)&PsT[m][ty * 4];
            float4 vv = *(const float4*)&VsT[m][tx * 4];
            float pa[4] = {pv.x, pv.y, pv.z, pv.w};
            float va[4] = {vv.x, vv.y, vv.z, vv.w};
#pragma unroll
            for (int i = 0; i < 4; ++i)
#pragma unroll
                for (int j = 0; j < 4; ++j)
                    o_acc[i][j] += pa[i] * va[j];
        }
        __syncthreads();   // protect Ks/VsT/PsT before next tile
    }

    // epilogue: divide by l, stage to LDS (PsT reused as Os[d][n]), store coalesced
    float inv_l[4];
#pragma unroll
    for (int i = 0; i < 4; ++i) inv_l[i] = 1.0f / l_run[i];
#pragma unroll
    for (int i = 0; i < 4; ++i)
#pragma unroll
        for (int j = 0; j < 4; ++j)
            PsT[tx * 4 + j][ty * 4 + i] = o_acc[i][j] * inv_l[i];
    __syncthreads();
    float* aob = ao + ((size_t)b * 256 + hh * 64) * NN;
#pragma unroll
    for (int i = 0; i < 16; ++i) {
        int idx = t + i * 256;
        int row = idx >> 6, col = idx & 63;
        aob[(size_t)row * NN + nt * 64 + col] = PsT[row][col];
    }
}

// ---------------------------------------------------------------------------
extern "C" void kernel_launch(void* const* d_in, const int* in_sizes, int n_in,
                              void* d_out, int out_size, void* d_ws, size_t ws_size,
                              hipStream_t stream)
{
    const float* x      = (const float*)d_in[0];
    const float* gamma  = (const float*)d_in[1];
    const float* beta   = (const float*)d_in[2];
    const float* qkv_w  = (const float*)d_in[3];
    const float* qkv_b  = (const float*)d_in[4];
    const float* proj_w = (const float*)d_in[5];
    const float* proj_b = (const float*)d_in[6];
    float* out = (float*)d_out;

    float*  ws    = (float*)d_ws;
    float2* stats = (float2*)ws;                       // 512 float2 = 1024 floats
    float*  qkv   = ws + 1024;                          // 16*768*1024 floats (48 MB)
    float*  ao    = qkv + (size_t)NB * 768 * NN;        // 16*256*1024 floats (16 MB)

    gn_stats_kernel<<<dim3(NB * 32), 256, 0, stream>>>(x, stats);

    // QKV projection with fused GroupNorm on the input
    gemm_kernel<true, false><<<dim3(16, 12, NB), 256, 0, stream>>>(
        qkv_w, qkv_b, x, stats, gamma, beta, nullptr, qkv, 768, 256);

    attn_kernel<<<dim3(16, 4, NB), 256, 0, stream>>>(qkv, ao);

    // Output projection with fused residual
    gemm_kernel<false, true><<<dim3(16, 4, NB), 256, 0, stream>>>(
        proj_w, proj_b, ao, nullptr, nullptr, nullptr, x, out, 256, 256);
}

// Round 2
// 266.077 us; speedup vs baseline: 1.8185x; 1.8185x over previous
//
#include <hip/hip_runtime.h>
#include <math.h>

typedef unsigned short u16;
typedef unsigned int u32;
typedef __attribute__((ext_vector_type(8))) short s16x8;
typedef __attribute__((ext_vector_type(4))) float f32x4;

#define NB 16
#define NN 1024
#define GN_EPS 1e-5f

static __device__ __forceinline__ u16 f2bf(float f) {
    union { float f; u32 u; } v; v.f = f;
    u32 r = (v.u + 0x7FFFu + ((v.u >> 16) & 1u)) >> 16;
    return (u16)r;
}
static __device__ __forceinline__ u32 pk2(float a, float b) {
    return (u32)f2bf(a) | ((u32)f2bf(b) << 16);
}

// ---------------------------------------------------------------------------
// Kernel 1: GroupNorm statistics. One block per (b, g); 8192 contiguous floats.
// ---------------------------------------------------------------------------
__global__ __launch_bounds__(256) void gn_stats_kernel(
    const float* __restrict__ x, float2* __restrict__ stats)
{
    const int bg = blockIdx.x;
    const int t  = threadIdx.x;
    const size_t base = (size_t)bg * 8192;
    float s = 0.f, ss = 0.f;
#pragma unroll
    for (int i = 0; i < 32; ++i) {
        float v = x[base + t + i * 256];
        s += v; ss += v * v;
    }
#pragma unroll
    for (int off = 32; off > 0; off >>= 1) {
        s  += __shfl_down(s, off);
        ss += __shfl_down(ss, off);
    }
    __shared__ float red[8];
    const int wid = t >> 6;
    if ((t & 63) == 0) { red[wid] = s; red[4 + wid] = ss; }
    __syncthreads();
    if (t == 0) {
        float sa = red[0] + red[1] + red[2] + red[3];
        float sb = red[4] + red[5] + red[6] + red[7];
        float mean = sa * (1.0f / 8192.0f);
        float var  = sb * (1.0f / 8192.0f) - mean * mean;
        stats[bg] = make_float2(mean, 1.0f / sqrtf(var + GN_EPS));
    }
}

// ---------------------------------------------------------------------------
// Kernel 2: QKV GEMM (fp32 VALU main loop, GN fused on X-tile load).
// Epilogue writes bf16: qh[n][d] (scaled 0.125), kh[m][d] (both via LDS
// transpose bounce), vh[d][m] direct.  o-tile == one (part, head) exactly.
// ---------------------------------------------------------------------------
__global__ __launch_bounds__(256) void qkv_gemm_kernel(
    const float* __restrict__ W, const float* __restrict__ bias,
    const float* __restrict__ X, const float2* __restrict__ stats,
    const float* __restrict__ gamma, const float* __restrict__ beta,
    u16* __restrict__ qh, u16* __restrict__ kh, u16* __restrict__ vh)
{
    const int b  = blockIdx.z;
    const int ot = blockIdx.y;   // 0..11
    const int nt = blockIdx.x;   // 0..15
    const int t  = threadIdx.x;
    const int tx = t & 15, ty = t >> 4;
    __shared__ float Wst[64][68];   // [k][o]
    __shared__ float Xs[64][68];    // [k][n]
    float acc[4][4] = {};
    const float* Xb = X + (size_t)b * 256 * NN;

    for (int kk = 0; kk < 256; kk += 64) {
#pragma unroll
        for (int i = 0; i < 16; ++i) {
            int idx = t + i * 256;
            int row = idx >> 6, col = idx & 63;
            Wst[col][row] = W[(size_t)(ot * 64 + row) * 256 + kk + col];
            float xv = Xb[(size_t)(kk + row) * NN + nt * 64 + col];
            int c = kk + row;
            float2 st = stats[b * 32 + (c >> 3)];
            xv = (xv - st.x) * st.y * gamma[c] + beta[c];
            Xs[row][col] = xv;
        }
        __syncthreads();
#pragma unroll 8
        for (int k = 0; k < 64; ++k) {
            float4 a  = *(const float4*)&Wst[k][ty * 4];
            float4 bb = *(const float4*)&Xs[k][tx * 4];
            float av[4] = {a.x, a.y, a.z, a.w};
            float bv[4] = {bb.x, bb.y, bb.z, bb.w};
#pragma unroll
            for (int i = 0; i < 4; ++i)
#pragma unroll
                for (int j = 0; j < 4; ++j)
                    acc[i][j] += av[i] * bv[j];
        }
        __syncthreads();
    }

    const int part = ot >> 2;        // 0=q 1=k 2=v
    const int h    = ot & 3;
    const size_t bhoff = (size_t)(b * 4 + h) << 16;   // *65536 elems per (b,h)

    if (part == 2) {
        // v: [d][m] bf16, direct coalesced 8B stores
#pragma unroll
        for (int i = 0; i < 4; ++i) {
            int d = ty * 4 + i;
            float bi = bias[ot * 64 + d];
            u32 lo = pk2(acc[i][0] + bi, acc[i][1] + bi);
            u32 hi = pk2(acc[i][2] + bi, acc[i][3] + bi);
            *(uint2*)(vh + bhoff + (size_t)d * NN + nt * 64 + tx * 4) = make_uint2(lo, hi);
        }
    } else {
        // q/k: transpose 64x64 tile via LDS, emit [n][d] bf16 rows
        float* T = &Wst[0][0];      // reused as [64][66]
        const float sc = (part == 0) ? 0.125f : 1.0f;
#pragma unroll
        for (int i = 0; i < 4; ++i) {
            float bi = bias[ot * 64 + ty * 4 + i];
#pragma unroll
            for (int j = 0; j < 4; ++j)
                T[(tx * 4 + j) * 66 + ty * 4 + i] = (acc[i][j] + bi) * sc;
        }
        __syncthreads();
        u16* dst = (part == 0 ? qh : kh) + bhoff;
#pragma unroll
        for (int pass = 0; pass < 2; ++pass) {
            int n = (t >> 3) + pass * 32;
            int s = t & 7;
            const float* src = T + n * 66 + s * 8;
            float2 f0 = *(const float2*)(src);
            float2 f1 = *(const float2*)(src + 2);
            float2 f2 = *(const float2*)(src + 4);
            float2 f3 = *(const float2*)(src + 6);
            s16x8 pv;
            pv[0] = (short)f2bf(f0.x); pv[1] = (short)f2bf(f0.y);
            pv[2] = (short)f2bf(f1.x); pv[3] = (short)f2bf(f1.y);
            pv[4] = (short)f2bf(f2.x); pv[5] = (short)f2bf(f2.y);
            pv[6] = (short)f2bf(f3.x); pv[7] = (short)f2bf(f3.y);
            *(s16x8*)(dst + (size_t)(nt * 64 + n) * 64 + s * 8) = pv;
        }
    }
}

// ---------------------------------------------------------------------------
// Kernel 3: MFMA flash attention.  Block = 4 waves x 32 queries = 128 queries.
// Wave: 2 n-tiles of 16.  S^T = K.Q^T (16x16x32 MFMA), softmax per-lane-col,
// P via wave-private frag-major LDS, O^T = V.P^T.  All LDS frag reads/writes
// are linear (base + lane*16B): conflict-free.
// ---------------------------------------------------------------------------
__global__ __launch_bounds__(256) void attn_mfma_kernel(
    const u16* __restrict__ qh, const u16* __restrict__ kh,
    const u16* __restrict__ vh, float* __restrict__ ao)
{
    const int t = threadIdx.x;
    const int w = t >> 6, l = t & 63;
    const int g = l >> 4, c = l & 15;
    const int b = blockIdx.z, h = blockIdx.y;
    const size_t bhoff = (size_t)(b * 4 + h) << 16;
    const int n_base = blockIdx.x * 128 + w * 32;

    __shared__ u16 Klds[8 * 512];       // pass (msub*2+u): frag-major
    __shared__ u16 Vlds[8 * 512];       // pass (dsub*2+u)
    __shared__ u16 Plds[4][4 * 512];    // per wave, pass (nt*2+u)

    const u16* qb = qh + bhoff;
    const u16* kb = kh + bhoff;
    const u16* vb = vh + bhoff;

    s16x8 qf[2][2];   // B-frags: Q[d = u*32+g*8+j][n_base+nt*16+c]
#pragma unroll
    for (int nt = 0; nt < 2; ++nt)
#pragma unroll
        for (int u = 0; u < 2; ++u)
            qf[nt][u] = *(const s16x8*)(qb + (size_t)(n_base + nt * 16 + c) * 64 + u * 32 + g * 8);

    f32x4 Oacc[2][4];
    float m_run[2], l_run[2];
#pragma unroll
    for (int nt = 0; nt < 2; ++nt) {
        m_run[nt] = -1e30f; l_run[nt] = 0.f;
#pragma unroll
        for (int ds = 0; ds < 4; ++ds) Oacc[nt][ds] = (f32x4){0.f, 0.f, 0.f, 0.f};
    }

    u16* pw = &Plds[w][0];

    for (int mt = 0; mt < 16; ++mt) {
        const int m0 = mt * 64;
        __syncthreads();
        // stage K tile (frag-major): lane slot <- k[m0+msub*16+c][u*32+g*8 ..+8]
#pragma unroll
        for (int pp = w; pp < 8; pp += 4) {
            int msub = pp >> 1, u = pp & 1;
            s16x8 kv = *(const s16x8*)(kb + (size_t)(m0 + msub * 16 + c) * 64 + u * 32 + g * 8);
            *(s16x8*)(Klds + pp * 512 + l * 8) = kv;
        }
        // stage V tile: lane slot <- v[dsub*16+c][m0+u*32+g*8 ..+8]
#pragma unroll
        for (int pp = w; pp < 8; pp += 4) {
            int dsub = pp >> 1, u = pp & 1;
            s16x8 vv = *(const s16x8*)(vb + (size_t)(dsub * 16 + c) * 1024 + m0 + u * 32 + g * 8);
            *(s16x8*)(Vlds + pp * 512 + l * 8) = vv;
        }
        __syncthreads();

        // QK^T: S^T[m][n], C layout row = g*4+r (m), col = c (n)
        f32x4 S[2][4];
#pragma unroll
        for (int nt = 0; nt < 2; ++nt)
#pragma unroll
            for (int ms = 0; ms < 4; ++ms) S[nt][ms] = (f32x4){0.f, 0.f, 0.f, 0.f};
#pragma unroll
        for (int ms = 0; ms < 4; ++ms)
#pragma unroll
            for (int u = 0; u < 2; ++u) {
                s16x8 af = *(const s16x8*)(Klds + (ms * 2 + u) * 512 + l * 8);
                S[0][ms] = __builtin_amdgcn_mfma_f32_16x16x32_bf16(af, qf[0][u], S[0][ms], 0, 0, 0);
                S[1][ms] = __builtin_amdgcn_mfma_f32_16x16x32_bf16(af, qf[1][u], S[1][ms], 0, 0, 0);
            }

        s16x8 vf[4][2];
#pragma unroll
        for (int ds = 0; ds < 4; ++ds)
#pragma unroll
            for (int u = 0; u < 2; ++u)
                vf[ds][u] = *(const s16x8*)(Vlds + (ds * 2 + u) * 512 + l * 8);

#pragma unroll
        for (int nt = 0; nt < 2; ++nt) {
            float tmax = -1e30f;
#pragma unroll
            for (int ms = 0; ms < 4; ++ms)
#pragma unroll
                for (int r = 0; r < 4; ++r) tmax = fmaxf(tmax, S[nt][ms][r]);
            tmax = fmaxf(tmax, __shfl_xor(tmax, 16));
            tmax = fmaxf(tmax, __shfl_xor(tmax, 32));
            float nm  = fmaxf(m_run[nt], tmax);
            float fac = __expf(m_run[nt] - nm);
            m_run[nt] = nm;
            float rsum = 0.f;
#pragma unroll
            for (int ms = 0; ms < 4; ++ms)
#pragma unroll
                for (int r = 0; r < 4; ++r) {
                    float p = __expf(S[nt][ms][r] - nm);
                    S[nt][ms][r] = p;
                    rsum += p;
                }
            rsum += __shfl_xor(rsum, 16);
            rsum += __shfl_xor(rsum, 32);
            l_run[nt] = l_run[nt] * fac + rsum;
#pragma unroll
            for (int ds = 0; ds < 4; ++ds)
#pragma unroll
                for (int r = 0; r < 4; ++r) Oacc[nt][ds][r] *= fac;
            // P store: m = ms*16+g*4+r -> pass u'=ms>>1, gg=(ms&1)*2+(g>>1), j=(g&1)*4+r
#pragma unroll
            for (int ms = 0; ms < 4; ++ms) {
                u32 d0 = pk2(S[nt][ms][0], S[nt][ms][1]);
                u32 d1 = pk2(S[nt][ms][2], S[nt][ms][3]);
                int off = (nt * 2 + (ms >> 1)) * 512 + ((ms & 1) * 2 + (g >> 1)) * 128 + c * 8 + (g & 1) * 4;
                *(uint2*)(pw + off) = make_uint2(d0, d1);
            }
        }
        asm volatile("s_waitcnt lgkmcnt(0)" ::: "memory");   // wave-private P ready
#pragma unroll
        for (int nt = 0; nt < 2; ++nt)
#pragma unroll
            for (int u = 0; u < 2; ++u) {
                s16x8 pf = *(const s16x8*)(pw + (nt * 2 + u) * 512 + l * 8);
#pragma unroll
                for (int ds = 0; ds < 4; ++ds)
                    Oacc[nt][ds] = __builtin_amdgcn_mfma_f32_16x16x32_bf16(vf[ds][u], pf, Oacc[nt][ds], 0, 0, 0);
            }
    }

    // O^T[d][n] / l  ->  ao[b][h*64+d][n]
    float* aob = ao + ((size_t)b * 256 + h * 64) * NN;
#pragma unroll
    for (int nt = 0; nt < 2; ++nt) {
        float inv = 1.0f / l_run[nt];
#pragma unroll
        for (int ds = 0; ds < 4; ++ds)
#pragma unroll
            for (int r = 0; r < 4; ++r) {
                int d = ds * 16 + g * 4 + r;
                aob[(size_t)d * NN + n_base + nt * 16 + c] = Oacc[nt][ds][r] * inv;
            }
    }
}

// ---------------------------------------------------------------------------
// Kernel 4: proj GEMM (fp32 VALU) with fused residual.
// ---------------------------------------------------------------------------
__global__ __launch_bounds__(256) void proj_gemm_kernel(
    const float* __restrict__ W, const float* __restrict__ bias,
    const float* __restrict__ X, const float* __restrict__ R,
    float* __restrict__ Y)
{
    const int b  = blockIdx.z;
    const int ot = blockIdx.y;
    const int nt = blockIdx.x;
    const int t  = threadIdx.x;
    const int tx = t & 15, ty = t >> 4;
    __shared__ float Wst[64][68];
    __shared__ float Xs[64][68];
    float acc[4][4] = {};
    const float* Xb = X + (size_t)b * 256 * NN;

    for (int kk = 0; kk < 256; kk += 64) {
#pragma unroll
        for (int i = 0; i < 16; ++i) {
            int idx = t + i * 256;
            int row = idx >> 6, col = idx & 63;
            Wst[col][row] = W[(size_t)(ot * 64 + row) * 256 + kk + col];
            Xs[row][col]  = Xb[(size_t)(kk + row) * NN + nt * 64 + col];
        }
        __syncthreads();
#pragma unroll 8
        for (int k = 0; k < 64; ++k) {
            float4 a  = *(const float4*)&Wst[k][ty * 4];
            float4 bb = *(const float4*)&Xs[k][tx * 4];
            float av[4] = {a.x, a.y, a.z, a.w};
            float bv[4] = {bb.x, bb.y, bb.z, bb.w};
#pragma unroll
            for (int i = 0; i < 4; ++i)
#pragma unroll
                for (int j = 0; j < 4; ++j)
                    acc[i][j] += av[i] * bv[j];
        }
        __syncthreads();
    }
    const int o0 = ot * 64 + ty * 4;
    const int n0 = nt * 64 + tx * 4;
#pragma unroll
    for (int i = 0; i < 4; ++i) {
        const int o = o0 + i;
        const float bi = bias[o];
        const size_t rowoff = ((size_t)b * 256 + o) * NN + n0;
#pragma unroll
        for (int j = 0; j < 4; ++j)
            Y[rowoff + j] = acc[i][j] + bi + R[rowoff + j];
    }
}

// ---------------------------------------------------------------------------
extern "C" void kernel_launch(void* const* d_in, const int* in_sizes, int n_in,
                              void* d_out, int out_size, void* d_ws, size_t ws_size,
                              hipStream_t stream)
{
    const float* x      = (const float*)d_in[0];
    const float* gamma  = (const float*)d_in[1];
    const float* beta   = (const float*)d_in[2];
    const float* qkv_w  = (const float*)d_in[3];
    const float* qkv_b  = (const float*)d_in[4];
    const float* proj_w = (const float*)d_in[5];
    const float* proj_b = (const float*)d_in[6];
    float* out = (float*)d_out;

    float*  ws    = (float*)d_ws;
    float2* stats = (float2*)ws;                 // 512 float2
    u16* qh = (u16*)(ws + 1024);                 // [B*4][1024 n][64 d] bf16
    u16* kh = qh + (size_t)4194304;              // [B*4][1024 m][64 d] bf16
    u16* vh = kh + (size_t)4194304;              // [B*4][64 d][1024 m] bf16
    float* ao = (float*)(vh + (size_t)4194304);  // [B][256][1024] fp32

    gn_stats_kernel<<<dim3(NB * 32), 256, 0, stream>>>(x, stats);

    qkv_gemm_kernel<<<dim3(16, 12, NB), 256, 0, stream>>>(
        qkv_w, qkv_b, x, stats, gamma, beta, qh, kh, vh);

    attn_mfma_kernel<<<dim3(8, 4, NB), 256, 0, stream>>>(qh, kh, vh, ao);

    proj_gemm_kernel<<<dim3(16, 4, NB), 256, 0, stream>>>(
        proj_w, proj_b, ao, x, out);
}

// Round 3
// 138.664 us; speedup vs baseline: 3.4894x; 1.9189x over previous
//
#include <hip/hip_runtime.h>
#include <math.h>

typedef unsigned short u16;
typedef unsigned int u32;
typedef __attribute__((ext_vector_type(8))) short s16x8;
typedef __attribute__((ext_vector_type(4))) float f32x4;

#define NB 16
#define NN 1024
#define GN_EPS 1e-5f

static __device__ __forceinline__ u16 f2bf(float f) {
    union { float f; u32 u; } v; v.f = f;
    u32 r = (v.u + 0x7FFFu + ((v.u >> 16) & 1u)) >> 16;
    return (u16)r;
}
static __device__ __forceinline__ u32 pk2(float a, float b) {
    return (u32)f2bf(a) | ((u32)f2bf(b) << 16);
}

// ---------------------------------------------------------------------------
// Kernel 1: GroupNorm statistics. One block per (b, g); 8192 contiguous floats.
// ---------------------------------------------------------------------------
__global__ __launch_bounds__(256) void gn_stats_kernel(
    const float* __restrict__ x, float2* __restrict__ stats)
{
    const int bg = blockIdx.x;
    const int t  = threadIdx.x;
    const size_t base = (size_t)bg * 8192;
    float s = 0.f, ss = 0.f;
#pragma unroll
    for (int i = 0; i < 32; ++i) {
        float v = x[base + t + i * 256];
        s += v; ss += v * v;
    }
#pragma unroll
    for (int off = 32; off > 0; off >>= 1) {
        s  += __shfl_down(s, off);
        ss += __shfl_down(ss, off);
    }
    __shared__ float red[8];
    const int wid = t >> 6;
    if ((t & 63) == 0) { red[wid] = s; red[4 + wid] = ss; }
    __syncthreads();
    if (t == 0) {
        float sa = red[0] + red[1] + red[2] + red[3];
        float sb = red[4] + red[5] + red[6] + red[7];
        float mean = sa * (1.0f / 8192.0f);
        float var  = sb * (1.0f / 8192.0f) - mean * mean;
        stats[bg] = make_float2(mean, 1.0f / sqrtf(var + GN_EPS));
    }
}

// ---------------------------------------------------------------------------
// Kernel 2: weights fp32 -> bf16 (contiguous). 65536 threads x 4 elems.
// ---------------------------------------------------------------------------
__global__ __launch_bounds__(256) void wcvt_kernel(
    const float* __restrict__ qkv_w, const float* __restrict__ proj_w,
    u16* __restrict__ wqb, u16* __restrict__ wpb)
{
    int i = blockIdx.x * 256 + threadIdx.x;   // 0..65535, 4 floats each
    if (i < 49152) {
        float4 f = ((const float4*)qkv_w)[i];
        *(uint2*)(wqb + (size_t)i * 4) = make_uint2(pk2(f.x, f.y), pk2(f.z, f.w));
    } else {
        int j = i - 49152;                    // 0..16383
        float4 f = ((const float4*)proj_w)[j];
        *(uint2*)(wpb + (size_t)j * 4) = make_uint2(pk2(f.x, f.y), pk2(f.z, f.w));
    }
}

// ---------------------------------------------------------------------------
// Kernel 3: GroupNorm-apply + transpose: x[b][c][n] fp32 -> Xt[b][n][c] bf16.
// 64x64 tiles via LDS.
// ---------------------------------------------------------------------------
__global__ __launch_bounds__(256) void gnorm_t_kernel(
    const float* __restrict__ x, const float2* __restrict__ stats,
    const float* __restrict__ gamma, const float* __restrict__ beta,
    u16* __restrict__ Xt)
{
    const int b = blockIdx.z, ct = blockIdx.y, nt = blockIdx.x;
    const int t = threadIdx.x;
    __shared__ float T[64][65];
    const float* xb = x + ((size_t)b * 256 + ct * 64) * NN + nt * 64;
#pragma unroll
    for (int i = 0; i < 16; ++i) {
        int idx = t + i * 256;
        int cr = idx >> 6, col = idx & 63;
        int ch = ct * 64 + cr;
        float2 st = stats[b * 32 + (ch >> 3)];
        float v = xb[(size_t)cr * NN + col];
        T[cr][col] = (v - st.x) * st.y * gamma[ch] + beta[ch];
    }
    __syncthreads();
    u16* dst = Xt + ((size_t)b * NN + nt * 64) * 256 + ct * 64;
#pragma unroll
    for (int p = 0; p < 2; ++p) {
        int idx = t + p * 256;
        int nl = idx >> 3, c8 = idx & 7;
        s16x8 pv;
#pragma unroll
        for (int j = 0; j < 8; ++j) pv[j] = (short)f2bf(T[c8 * 8 + j][nl]);
        *(s16x8*)(dst + (size_t)nl * 256 + c8 * 8) = pv;
    }
}

// ---------------------------------------------------------------------------
// Kernel 4: QKV GEMM, bf16 MFMA. Block: 128n x 64o slab x K=256 (full K in LDS,
// frag-major slots, one barrier). ot = part*4 + h. q/k computed with swapped
// operands -> C[n][d] directly; v normal -> C[d][m].
// ---------------------------------------------------------------------------
__global__ __launch_bounds__(256) void qkv_mfma_kernel(
    const u16* __restrict__ Wb, const float* __restrict__ bias,
    const u16* __restrict__ Xt,
    u16* __restrict__ qh, u16* __restrict__ kh, u16* __restrict__ vh)
{
    const int b = blockIdx.z, ot = blockIdx.y, nt = blockIdx.x;
    const int t = threadIdx.x, w = t >> 6, l = t & 63;
    const int g = l >> 4, c = l & 15;
    __shared__ u16 Xlds[64 * 512];   // slot (nsub*8+ks): frag-major 16n x 32k
    __shared__ u16 Wlds[32 * 512];   // slot (osub*8+ks)
    const u16* Xb = Xt + ((size_t)b * NN + nt * 128) * 256;
    const u16* Wo = Wb + (size_t)ot * 64 * 256;

#pragma unroll
    for (int s = w; s < 64; s += 4) {
        int nsub = s >> 3, ks = s & 7;
        s16x8 v = *(const s16x8*)(Xb + (size_t)(nsub * 16 + c) * 256 + ks * 32 + g * 8);
        *(s16x8*)(Xlds + s * 512 + l * 8) = v;
    }
#pragma unroll
    for (int s = w; s < 32; s += 4) {
        int osub = s >> 3, ks = s & 7;
        s16x8 v = *(const s16x8*)(Wo + (size_t)(osub * 16 + c) * 256 + ks * 32 + g * 8);
        *(s16x8*)(Wlds + s * 512 + l * 8) = v;
    }
    __syncthreads();

    const int part = ot >> 2, h = ot & 3;
    const size_t bhoff = (size_t)(b * 4 + h) << 16;

    if (part < 2) {
        // C[n][o]: wave owns nsubs {2w,2w+1} x 4 o-frags
        f32x4 acc[2][4];
#pragma unroll
        for (int i = 0; i < 2; ++i)
#pragma unroll
            for (int j = 0; j < 4; ++j) acc[i][j] = (f32x4){0.f, 0.f, 0.f, 0.f};
#pragma unroll
        for (int ks = 0; ks < 8; ++ks) {
            s16x8 a0 = *(const s16x8*)(Xlds + ((2 * w) * 8 + ks) * 512 + l * 8);
            s16x8 a1 = *(const s16x8*)(Xlds + ((2 * w + 1) * 8 + ks) * 512 + l * 8);
#pragma unroll
            for (int j = 0; j < 4; ++j) {
                s16x8 bf = *(const s16x8*)(Wlds + (j * 8 + ks) * 512 + l * 8);
                acc[0][j] = __builtin_amdgcn_mfma_f32_16x16x32_bf16(a0, bf, acc[0][j], 0, 0, 0);
                acc[1][j] = __builtin_amdgcn_mfma_f32_16x16x32_bf16(a1, bf, acc[1][j], 0, 0, 0);
            }
        }
        const float sc = (part == 0) ? 0.125f : 1.0f;
        float bv[4];
#pragma unroll
        for (int j = 0; j < 4; ++j) bv[j] = bias[ot * 64 + j * 16 + c];
        u16* dst = (part == 0 ? qh : kh) + bhoff + (size_t)(nt * 128) * 64;
#pragma unroll
        for (int i = 0; i < 2; ++i)
#pragma unroll
            for (int j = 0; j < 4; ++j)
#pragma unroll
                for (int r = 0; r < 4; ++r) {
                    int n = (2 * w + i) * 16 + g * 4 + r;
                    dst[(size_t)n * 64 + j * 16 + c] = f2bf((acc[i][j][r] + bv[j]) * sc);
                }
    } else {
        // C[d][m]: wave owns osub w x 8 n-frags
        f32x4 acc[8];
#pragma unroll
        for (int j = 0; j < 8; ++j) acc[j] = (f32x4){0.f, 0.f, 0.f, 0.f};
#pragma unroll
        for (int ks = 0; ks < 8; ++ks) {
            s16x8 a = *(const s16x8*)(Wlds + (w * 8 + ks) * 512 + l * 8);
#pragma unroll
            for (int j = 0; j < 8; ++j) {
                s16x8 xf = *(const s16x8*)(Xlds + (j * 8 + ks) * 512 + l * 8);
                acc[j] = __builtin_amdgcn_mfma_f32_16x16x32_bf16(a, xf, acc[j], 0, 0, 0);
            }
        }
        float bv[4];
#pragma unroll
        for (int r = 0; r < 4; ++r) bv[r] = bias[ot * 64 + w * 16 + g * 4 + r];
        u16* dst = vh + bhoff;
#pragma unroll
        for (int j = 0; j < 8; ++j)
#pragma unroll
            for (int r = 0; r < 4; ++r) {
                int d = w * 16 + g * 4 + r;
                int m = nt * 128 + j * 16 + c;
                dst[(size_t)d * NN + m] = f2bf(acc[j][r] + bv[r]);
            }
    }
}

// ---------------------------------------------------------------------------
// Kernel 5: MFMA flash attention (unchanged core). Output now aoT[b][n][256]
// bf16 at col h*64 (k-contiguous for the proj MFMA).
// ---------------------------------------------------------------------------
__global__ __launch_bounds__(256) void attn_mfma_kernel(
    const u16* __restrict__ qh, const u16* __restrict__ kh,
    const u16* __restrict__ vh, u16* __restrict__ aoT)
{
    const int t = threadIdx.x;
    const int w = t >> 6, l = t & 63;
    const int g = l >> 4, c = l & 15;
    const int b = blockIdx.z, h = blockIdx.y;
    const size_t bhoff = (size_t)(b * 4 + h) << 16;
    const int n_base = blockIdx.x * 128 + w * 32;

    __shared__ u16 Klds[8 * 512];
    __shared__ u16 Vlds[8 * 512];
    __shared__ u16 Plds[4][4 * 512];

    const u16* qb = qh + bhoff;
    const u16* kb = kh + bhoff;
    const u16* vb = vh + bhoff;

    s16x8 qf[2][2];
#pragma unroll
    for (int nt = 0; nt < 2; ++nt)
#pragma unroll
        for (int u = 0; u < 2; ++u)
            qf[nt][u] = *(const s16x8*)(qb + (size_t)(n_base + nt * 16 + c) * 64 + u * 32 + g * 8);

    f32x4 Oacc[2][4];
    float m_run[2], l_run[2];
#pragma unroll
    for (int nt = 0; nt < 2; ++nt) {
        m_run[nt] = -1e30f; l_run[nt] = 0.f;
#pragma unroll
        for (int ds = 0; ds < 4; ++ds) Oacc[nt][ds] = (f32x4){0.f, 0.f, 0.f, 0.f};
    }

    u16* pw = &Plds[w][0];

    for (int mt = 0; mt < 16; ++mt) {
        const int m0 = mt * 64;
        __syncthreads();
#pragma unroll
        for (int pp = w; pp < 8; pp += 4) {
            int msub = pp >> 1, u = pp & 1;
            s16x8 kv = *(const s16x8*)(kb + (size_t)(m0 + msub * 16 + c) * 64 + u * 32 + g * 8);
            *(s16x8*)(Klds + pp * 512 + l * 8) = kv;
        }
#pragma unroll
        for (int pp = w; pp < 8; pp += 4) {
            int dsub = pp >> 1, u = pp & 1;
            s16x8 vv = *(const s16x8*)(vb + (size_t)(dsub * 16 + c) * NN + m0 + u * 32 + g * 8);
            *(s16x8*)(Vlds + pp * 512 + l * 8) = vv;
        }
        __syncthreads();

        f32x4 S[2][4];
#pragma unroll
        for (int nt = 0; nt < 2; ++nt)
#pragma unroll
            for (int ms = 0; ms < 4; ++ms) S[nt][ms] = (f32x4){0.f, 0.f, 0.f, 0.f};
#pragma unroll
        for (int ms = 0; ms < 4; ++ms)
#pragma unroll
            for (int u = 0; u < 2; ++u) {
                s16x8 af = *(const s16x8*)(Klds + (ms * 2 + u) * 512 + l * 8);
                S[0][ms] = __builtin_amdgcn_mfma_f32_16x16x32_bf16(af, qf[0][u], S[0][ms], 0, 0, 0);
                S[1][ms] = __builtin_amdgcn_mfma_f32_16x16x32_bf16(af, qf[1][u], S[1][ms], 0, 0, 0);
            }

        s16x8 vf[4][2];
#pragma unroll
        for (int ds = 0; ds < 4; ++ds)
#pragma unroll
            for (int u = 0; u < 2; ++u)
                vf[ds][u] = *(const s16x8*)(Vlds + (ds * 2 + u) * 512 + l * 8);

#pragma unroll
        for (int nt = 0; nt < 2; ++nt) {
            float tmax = -1e30f;
#pragma unroll
            for (int ms = 0; ms < 4; ++ms)
#pragma unroll
                for (int r = 0; r < 4; ++r) tmax = fmaxf(tmax, S[nt][ms][r]);
            tmax = fmaxf(tmax, __shfl_xor(tmax, 16));
            tmax = fmaxf(tmax, __shfl_xor(tmax, 32));
            float nm  = fmaxf(m_run[nt], tmax);
            float fac = __expf(m_run[nt] - nm);
            m_run[nt] = nm;
            float rsum = 0.f;
#pragma unroll
            for (int ms = 0; ms < 4; ++ms)
#pragma unroll
                for (int r = 0; r < 4; ++r) {
                    float p = __expf(S[nt][ms][r] - nm);
                    S[nt][ms][r] = p;
                    rsum += p;
                }
            rsum += __shfl_xor(rsum, 16);
            rsum += __shfl_xor(rsum, 32);
            l_run[nt] = l_run[nt] * fac + rsum;
#pragma unroll
            for (int ds = 0; ds < 4; ++ds)
#pragma unroll
                for (int r = 0; r < 4; ++r) Oacc[nt][ds][r] *= fac;
#pragma unroll
            for (int ms = 0; ms < 4; ++ms) {
                u32 d0 = pk2(S[nt][ms][0], S[nt][ms][1]);
                u32 d1 = pk2(S[nt][ms][2], S[nt][ms][3]);
                int off = (nt * 2 + (ms >> 1)) * 512 + ((ms & 1) * 2 + (g >> 1)) * 128 + c * 8 + (g & 1) * 4;
                *(uint2*)(pw + off) = make_uint2(d0, d1);
            }
        }
        asm volatile("s_waitcnt lgkmcnt(0)" ::: "memory");
#pragma unroll
        for (int nt = 0; nt < 2; ++nt)
#pragma unroll
            for (int u = 0; u < 2; ++u) {
                s16x8 pf = *(const s16x8*)(pw + (nt * 2 + u) * 512 + l * 8);
#pragma unroll
                for (int ds = 0; ds < 4; ++ds)
                    Oacc[nt][ds] = __builtin_amdgcn_mfma_f32_16x16x32_bf16(vf[ds][u], pf, Oacc[nt][ds], 0, 0, 0);
            }
    }

    // write aoT[b][n][h*64 + d] bf16, d packed 4-wide
    u16* aob = aoT + (size_t)b * NN * 256 + h * 64;
#pragma unroll
    for (int nt = 0; nt < 2; ++nt) {
        float inv = 1.0f / l_run[nt];
        const size_t nrow = (size_t)(n_base + nt * 16 + c) * 256;
#pragma unroll
        for (int ds = 0; ds < 4; ++ds) {
            u32 lo = pk2(Oacc[nt][ds][0] * inv, Oacc[nt][ds][1] * inv);
            u32 hi = pk2(Oacc[nt][ds][2] * inv, Oacc[nt][ds][3] * inv);
            *(uint2*)(aob + nrow + ds * 16 + g * 4) = make_uint2(lo, hi);
        }
    }
}

// ---------------------------------------------------------------------------
// Kernel 6: proj GEMM, bf16 MFMA, C[o][n], fused bias + fp32 residual.
// ---------------------------------------------------------------------------
__global__ __launch_bounds__(256) void proj_mfma_kernel(
    const u16* __restrict__ Wb, const float* __restrict__ bias,
    const u16* __restrict__ aoT, const float* __restrict__ x,
    float* __restrict__ out)
{
    const int b = blockIdx.z, ot = blockIdx.y, nt = blockIdx.x;
    const int t = threadIdx.x, w = t >> 6, l = t & 63;
    const int g = l >> 4, c = l & 15;
    __shared__ u16 Xlds[64 * 512];
    __shared__ u16 Wlds[32 * 512];
    const u16* Xb = aoT + ((size_t)b * NN + nt * 128) * 256;
    const u16* Wo = Wb + (size_t)ot * 64 * 256;

#pragma unroll
    for (int s = w; s < 64; s += 4) {
        int nsub = s >> 3, ks = s & 7;
        s16x8 v = *(const s16x8*)(Xb + (size_t)(nsub * 16 + c) * 256 + ks * 32 + g * 8);
        *(s16x8*)(Xlds + s * 512 + l * 8) = v;
    }
#pragma unroll
    for (int s = w; s < 32; s += 4) {
        int osub = s >> 3, ks = s & 7;
        s16x8 v = *(const s16x8*)(Wo + (size_t)(osub * 16 + c) * 256 + ks * 32 + g * 8);
        *(s16x8*)(Wlds + s * 512 + l * 8) = v;
    }
    __syncthreads();

    f32x4 acc[8];
#pragma unroll
    for (int j = 0; j < 8; ++j) acc[j] = (f32x4){0.f, 0.f, 0.f, 0.f};
#pragma unroll
    for (int ks = 0; ks < 8; ++ks) {
        s16x8 a = *(const s16x8*)(Wlds + (w * 8 + ks) * 512 + l * 8);
#pragma unroll
        for (int j = 0; j < 8; ++j) {
            s16x8 xf = *(const s16x8*)(Xlds + (j * 8 + ks) * 512 + l * 8);
            acc[j] = __builtin_amdgcn_mfma_f32_16x16x32_bf16(a, xf, acc[j], 0, 0, 0);
        }
    }
    float bv[4];
#pragma unroll
    for (int r = 0; r < 4; ++r) bv[r] = bias[ot * 64 + w * 16 + g * 4 + r];
#pragma unroll
    for (int j = 0; j < 8; ++j)
#pragma unroll
        for (int r = 0; r < 4; ++r) {
            int o = ot * 64 + w * 16 + g * 4 + r;
            int n = nt * 128 + j * 16 + c;
            size_t addr = ((size_t)b * 256 + o) * NN + n;
            out[addr] = acc[j][r] + bv[r] + x[addr];
        }
}

// ---------------------------------------------------------------------------
extern "C" void kernel_launch(void* const* d_in, const int* in_sizes, int n_in,
                              void* d_out, int out_size, void* d_ws, size_t ws_size,
                              hipStream_t stream)
{
    const float* x      = (const float*)d_in[0];
    const float* gamma  = (const float*)d_in[1];
    const float* beta   = (const float*)d_in[2];
    const float* qkv_w  = (const float*)d_in[3];
    const float* qkv_b  = (const float*)d_in[4];
    const float* proj_w = (const float*)d_in[5];
    const float* proj_b = (const float*)d_in[6];
    float* out = (float*)d_out;

    float* ws = (float*)d_ws;
    float2* stats = (float2*)ws;                  // 4 KB
    u16* Xt  = (u16*)(ws + 1024);                 // [B][1024 n][256 c]
    u16* wqb = Xt + (size_t)4194304;              // [768][256]
    u16* wpb = wqb + (size_t)196608;              // [256][256]
    u16* qh  = wpb + (size_t)65536;               // [B*4][1024 n][64 d]
    u16* kh  = qh + (size_t)4194304;              // [B*4][1024 m][64 d]
    u16* vh  = kh + (size_t)4194304;              // [B*4][64 d][1024 m]
    u16* aoT = vh + (size_t)4194304;              // [B][1024 n][256 c]

    gn_stats_kernel<<<dim3(NB * 32), 256, 0, stream>>>(x, stats);
    wcvt_kernel<<<dim3(256), 256, 0, stream>>>(qkv_w, proj_w, wqb, wpb);
    gnorm_t_kernel<<<dim3(16, 4, NB), 256, 0, stream>>>(x, stats, gamma, beta, Xt);

    qkv_mfma_kernel<<<dim3(8, 12, NB), 256, 0, stream>>>(
        wqb, qkv_b, Xt, qh, kh, vh);

    attn_mfma_kernel<<<dim3(8, 4, NB), 256, 0, stream>>>(qh, kh, vh, aoT);

    proj_mfma_kernel<<<dim3(8, 4, NB), 256, 0, stream>>>(
        wpb, proj_b, aoT, x, out);
}

// Round 4
// 133.609 us; speedup vs baseline: 3.6214x; 1.0378x over previous
//
#include <hip/hip_runtime.h>
#include <math.h>

typedef unsigned short u16;
typedef unsigned int u32;
typedef __attribute__((ext_vector_type(8))) short s16x8;
typedef __attribute__((ext_vector_type(4))) float f32x4;

#define NB 16
#define NN 1024
#define GN_EPS 1e-5f

// cheap bf16 round (ties-away): 2 VALU ops
static __device__ __forceinline__ u16 f2bf(float f) {
    union { float f; u32 u; } v; v.f = f;
    return (u16)((v.u + 0x8000u) >> 16);
}
// pack two floats -> two bf16 in one u32: 2 adds + 1 v_perm_b32
static __device__ __forceinline__ u32 pk2(float a, float b) {
    union { float f; u32 u; } A, B; A.f = a; B.f = b;
    return __builtin_amdgcn_perm(A.u + 0x8000u, B.u + 0x8000u, 0x03020706u);
}

// ---------------------------------------------------------------------------
// Kernel 1: GroupNorm statistics. One block per (b, g); 8192 contiguous floats.
// ---------------------------------------------------------------------------
__global__ __launch_bounds__(256) void gn_stats_kernel(
    const float* __restrict__ x, float2* __restrict__ stats)
{
    const int bg = blockIdx.x;
    const int t  = threadIdx.x;
    const size_t base = (size_t)bg * 8192;
    float s = 0.f, ss = 0.f;
#pragma unroll
    for (int i = 0; i < 32; ++i) {
        float v = x[base + t + i * 256];
        s += v; ss += v * v;
    }
#pragma unroll
    for (int off = 32; off > 0; off >>= 1) {
        s  += __shfl_down(s, off);
        ss += __shfl_down(ss, off);
    }
    __shared__ float red[8];
    const int wid = t >> 6;
    if ((t & 63) == 0) { red[wid] = s; red[4 + wid] = ss; }
    __syncthreads();
    if (t == 0) {
        float sa = red[0] + red[1] + red[2] + red[3];
        float sb = red[4] + red[5] + red[6] + red[7];
        float mean = sa * (1.0f / 8192.0f);
        float var  = sb * (1.0f / 8192.0f) - mean * mean;
        stats[bg] = make_float2(mean, 1.0f / sqrtf(var + GN_EPS));
    }
}

// ---------------------------------------------------------------------------
// Kernel 2: weights fp32 -> bf16 (contiguous). 65536 threads x 4 elems.
// ---------------------------------------------------------------------------
__global__ __launch_bounds__(256) void wcvt_kernel(
    const float* __restrict__ qkv_w, const float* __restrict__ proj_w,
    u16* __restrict__ wqb, u16* __restrict__ wpb)
{
    int i = blockIdx.x * 256 + threadIdx.x;   // 0..65535, 4 floats each
    if (i < 49152) {
        float4 f = ((const float4*)qkv_w)[i];
        *(uint2*)(wqb + (size_t)i * 4) = make_uint2(pk2(f.x, f.y), pk2(f.z, f.w));
    } else {
        int j = i - 49152;                    // 0..16383
        float4 f = ((const float4*)proj_w)[j];
        *(uint2*)(wpb + (size_t)j * 4) = make_uint2(pk2(f.x, f.y), pk2(f.z, f.w));
    }
}

// ---------------------------------------------------------------------------
// Kernel 3: GroupNorm-apply + transpose: x[b][c][n] fp32 -> Xt[b][n][c] bf16.
// ---------------------------------------------------------------------------
__global__ __launch_bounds__(256) void gnorm_t_kernel(
    const float* __restrict__ x, const float2* __restrict__ stats,
    const float* __restrict__ gamma, const float* __restrict__ beta,
    u16* __restrict__ Xt)
{
    const int b = blockIdx.z, ct = blockIdx.y, nt = blockIdx.x;
    const int t = threadIdx.x;
    __shared__ float T[64][65];
    const float* xb = x + ((size_t)b * 256 + ct * 64) * NN + nt * 64;
#pragma unroll
    for (int i = 0; i < 16; ++i) {
        int idx = t + i * 256;
        int cr = idx >> 6, col = idx & 63;
        int ch = ct * 64 + cr;
        float2 st = stats[b * 32 + (ch >> 3)];
        float v = xb[(size_t)cr * NN + col];
        T[cr][col] = (v - st.x) * st.y * gamma[ch] + beta[ch];
    }
    __syncthreads();
    u16* dst = Xt + ((size_t)b * NN + nt * 64) * 256 + ct * 64;
#pragma unroll
    for (int p = 0; p < 2; ++p) {
        int idx = t + p * 256;
        int nl = idx >> 3, c8 = idx & 7;
        s16x8 pv;
#pragma unroll
        for (int j = 0; j < 8; ++j) pv[j] = (short)f2bf(T[c8 * 8 + j][nl]);
        *(s16x8*)(dst + (size_t)nl * 256 + c8 * 8) = pv;
    }
}

// ---------------------------------------------------------------------------
// Kernel 4: QKV GEMM, bf16 MFMA. Block: 128n x 64o slab x K=256 in LDS.
// ---------------------------------------------------------------------------
__global__ __launch_bounds__(256) void qkv_mfma_kernel(
    const u16* __restrict__ Wb, const float* __restrict__ bias,
    const u16* __restrict__ Xt,
    u16* __restrict__ qh, u16* __restrict__ kh, u16* __restrict__ vh)
{
    const int b = blockIdx.z, ot = blockIdx.y, nt = blockIdx.x;
    const int t = threadIdx.x, w = t >> 6, l = t & 63;
    const int g = l >> 4, c = l & 15;
    __shared__ u16 Xlds[64 * 512];
    __shared__ u16 Wlds[32 * 512];
    const u16* Xb = Xt + ((size_t)b * NN + nt * 128) * 256;
    const u16* Wo = Wb + (size_t)ot * 64 * 256;

#pragma unroll
    for (int s = w; s < 64; s += 4) {
        int nsub = s >> 3, ks = s & 7;
        s16x8 v = *(const s16x8*)(Xb + (size_t)(nsub * 16 + c) * 256 + ks * 32 + g * 8);
        *(s16x8*)(Xlds + s * 512 + l * 8) = v;
    }
#pragma unroll
    for (int s = w; s < 32; s += 4) {
        int osub = s >> 3, ks = s & 7;
        s16x8 v = *(const s16x8*)(Wo + (size_t)(osub * 16 + c) * 256 + ks * 32 + g * 8);
        *(s16x8*)(Wlds + s * 512 + l * 8) = v;
    }
    __syncthreads();

    const int part = ot >> 2, h = ot & 3;
    const size_t bhoff = (size_t)(b * 4 + h) << 16;

    if (part < 2) {
        f32x4 acc[2][4];
#pragma unroll
        for (int i = 0; i < 2; ++i)
#pragma unroll
            for (int j = 0; j < 4; ++j) acc[i][j] = (f32x4){0.f, 0.f, 0.f, 0.f};
#pragma unroll
        for (int ks = 0; ks < 8; ++ks) {
            s16x8 a0 = *(const s16x8*)(Xlds + ((2 * w) * 8 + ks) * 512 + l * 8);
            s16x8 a1 = *(const s16x8*)(Xlds + ((2 * w + 1) * 8 + ks) * 512 + l * 8);
#pragma unroll
            for (int j = 0; j < 4; ++j) {
                s16x8 bf = *(const s16x8*)(Wlds + (j * 8 + ks) * 512 + l * 8);
                acc[0][j] = __builtin_amdgcn_mfma_f32_16x16x32_bf16(a0, bf, acc[0][j], 0, 0, 0);
                acc[1][j] = __builtin_amdgcn_mfma_f32_16x16x32_bf16(a1, bf, acc[1][j], 0, 0, 0);
            }
        }
        const float sc = (part == 0) ? 0.125f : 1.0f;
        float bv[4];
#pragma unroll
        for (int j = 0; j < 4; ++j) bv[j] = bias[ot * 64 + j * 16 + c];
        u16* dst = (part == 0 ? qh : kh) + bhoff + (size_t)(nt * 128) * 64;
#pragma unroll
        for (int i = 0; i < 2; ++i)
#pragma unroll
            for (int j = 0; j < 4; ++j)
#pragma unroll
                for (int r = 0; r < 4; ++r) {
                    int n = (2 * w + i) * 16 + g * 4 + r;
                    dst[(size_t)n * 64 + j * 16 + c] = f2bf((acc[i][j][r] + bv[j]) * sc);
                }
    } else {
        f32x4 acc[8];
#pragma unroll
        for (int j = 0; j < 8; ++j) acc[j] = (f32x4){0.f, 0.f, 0.f, 0.f};
#pragma unroll
        for (int ks = 0; ks < 8; ++ks) {
            s16x8 a = *(const s16x8*)(Wlds + (w * 8 + ks) * 512 + l * 8);
#pragma unroll
            for (int j = 0; j < 8; ++j) {
                s16x8 xf = *(const s16x8*)(Xlds + (j * 8 + ks) * 512 + l * 8);
                acc[j] = __builtin_amdgcn_mfma_f32_16x16x32_bf16(a, xf, acc[j], 0, 0, 0);
            }
        }
        float bv[4];
#pragma unroll
        for (int r = 0; r < 4; ++r) bv[r] = bias[ot * 64 + w * 16 + g * 4 + r];
        u16* dst = vh + bhoff;
#pragma unroll
        for (int j = 0; j < 8; ++j)
#pragma unroll
            for (int r = 0; r < 4; ++r) {
                int d = w * 16 + g * 4 + r;
                int m = nt * 128 + j * 16 + c;
                dst[(size_t)d * NN + m] = f2bf(acc[j][r] + bv[r]);
            }
    }
}

// ---------------------------------------------------------------------------
// Kernel 5: MFMA flash attention. 1-D grid 512, XCD-swizzled so all 8 q-tile
// blocks of one (b,h) share bid%8 (same XCD L2). Defer-max THR=8.
// ---------------------------------------------------------------------------
__global__ __launch_bounds__(256) void attn_mfma_kernel(
    const u16* __restrict__ qh, const u16* __restrict__ kh,
    const u16* __restrict__ vh, u16* __restrict__ aoT)
{
    const int t = threadIdx.x;
    const int w = t >> 6, l = t & 63;
    const int g = l >> 4, c = l & 15;
    // swizzle: bid = xcd + 8*(qt + 8*gi); group g = gi*8 + xcd
    const int bid = blockIdx.x;
    const int xcd = bid & 7;
    const int idx = bid >> 3;
    const int qt  = idx & 7;
    const int grp = (idx >> 3) * 8 + xcd;     // 0..63
    const int b = grp >> 2, h = grp & 3;
    const size_t bhoff = (size_t)grp << 16;
    const int n_base = qt * 128 + w * 32;

    __shared__ u16 Klds[8 * 512];
    __shared__ u16 Vlds[8 * 512];
    __shared__ u16 Plds[4][4 * 512];

    const u16* qb = qh + bhoff;
    const u16* kb = kh + bhoff;
    const u16* vb = vh + bhoff;

    s16x8 qf[2][2];
#pragma unroll
    for (int nt = 0; nt < 2; ++nt)
#pragma unroll
        for (int u = 0; u < 2; ++u)
            qf[nt][u] = *(const s16x8*)(qb + (size_t)(n_base + nt * 16 + c) * 64 + u * 32 + g * 8);

    f32x4 Oacc[2][4];
    float m_run[2], l_run[2];
#pragma unroll
    for (int nt = 0; nt < 2; ++nt) {
        m_run[nt] = -1e30f; l_run[nt] = 0.f;
#pragma unroll
        for (int ds = 0; ds < 4; ++ds) Oacc[nt][ds] = (f32x4){0.f, 0.f, 0.f, 0.f};
    }

    u16* pw = &Plds[w][0];

    for (int mt = 0; mt < 16; ++mt) {
        const int m0 = mt * 64;
        __syncthreads();
#pragma unroll
        for (int pp = w; pp < 8; pp += 4) {
            int msub = pp >> 1, u = pp & 1;
            s16x8 kv = *(const s16x8*)(kb + (size_t)(m0 + msub * 16 + c) * 64 + u * 32 + g * 8);
            *(s16x8*)(Klds + pp * 512 + l * 8) = kv;
        }
#pragma unroll
        for (int pp = w; pp < 8; pp += 4) {
            int dsub = pp >> 1, u = pp & 1;
            s16x8 vv = *(const s16x8*)(vb + (size_t)(dsub * 16 + c) * NN + m0 + u * 32 + g * 8);
            *(s16x8*)(Vlds + pp * 512 + l * 8) = vv;
        }
        __syncthreads();

        f32x4 S[2][4];
#pragma unroll
        for (int nt = 0; nt < 2; ++nt)
#pragma unroll
            for (int ms = 0; ms < 4; ++ms) S[nt][ms] = (f32x4){0.f, 0.f, 0.f, 0.f};
#pragma unroll
        for (int ms = 0; ms < 4; ++ms)
#pragma unroll
            for (int u = 0; u < 2; ++u) {
                s16x8 af = *(const s16x8*)(Klds + (ms * 2 + u) * 512 + l * 8);
                S[0][ms] = __builtin_amdgcn_mfma_f32_16x16x32_bf16(af, qf[0][u], S[0][ms], 0, 0, 0);
                S[1][ms] = __builtin_amdgcn_mfma_f32_16x16x32_bf16(af, qf[1][u], S[1][ms], 0, 0, 0);
            }

        s16x8 vf[4][2];
#pragma unroll
        for (int ds = 0; ds < 4; ++ds)
#pragma unroll
            for (int u = 0; u < 2; ++u)
                vf[ds][u] = *(const s16x8*)(Vlds + (ds * 2 + u) * 512 + l * 8);

#pragma unroll
        for (int nt = 0; nt < 2; ++nt) {
            float tmax = -1e30f;
#pragma unroll
            for (int ms = 0; ms < 4; ++ms)
#pragma unroll
                for (int r = 0; r < 4; ++r) tmax = fmaxf(tmax, S[nt][ms][r]);
            tmax = fmaxf(tmax, __shfl_xor(tmax, 16));
            tmax = fmaxf(tmax, __shfl_xor(tmax, 32));
            // defer-max: rescale only if some column grew by > 8
            if (!__all(tmax <= m_run[nt] + 8.f)) {
                float nm  = fmaxf(m_run[nt], tmax);
                float fac = __expf(m_run[nt] - nm);
                m_run[nt] = nm;
                l_run[nt] *= fac;
#pragma unroll
                for (int ds = 0; ds < 4; ++ds)
#pragma unroll
                    for (int r = 0; r < 4; ++r) Oacc[nt][ds][r] *= fac;
            }
            const float mm = m_run[nt];
            float rsum = 0.f;
#pragma unroll
            for (int ms = 0; ms < 4; ++ms)
#pragma unroll
                for (int r = 0; r < 4; ++r) {
                    float p = __expf(S[nt][ms][r] - mm);
                    S[nt][ms][r] = p;
                    rsum += p;
                }
            rsum += __shfl_xor(rsum, 16);
            rsum += __shfl_xor(rsum, 32);
            l_run[nt] += rsum;
#pragma unroll
            for (int ms = 0; ms < 4; ++ms) {
                u32 d0 = pk2(S[nt][ms][0], S[nt][ms][1]);
                u32 d1 = pk2(S[nt][ms][2], S[nt][ms][3]);
                int off = (nt * 2 + (ms >> 1)) * 512 + ((ms & 1) * 2 + (g >> 1)) * 128 + c * 8 + (g & 1) * 4;
                *(uint2*)(pw + off) = make_uint2(d0, d1);
            }
        }
        asm volatile("s_waitcnt lgkmcnt(0)" ::: "memory");
#pragma unroll
        for (int nt = 0; nt < 2; ++nt)
#pragma unroll
            for (int u = 0; u < 2; ++u) {
                s16x8 pf = *(const s16x8*)(pw + (nt * 2 + u) * 512 + l * 8);
#pragma unroll
                for (int ds = 0; ds < 4; ++ds)
                    Oacc[nt][ds] = __builtin_amdgcn_mfma_f32_16x16x32_bf16(vf[ds][u], pf, Oacc[nt][ds], 0, 0, 0);
            }
    }

    u16* aob = aoT + (size_t)b * NN * 256 + h * 64;
#pragma unroll
    for (int nt = 0; nt < 2; ++nt) {
        float inv = 1.0f / l_run[nt];
        const size_t nrow = (size_t)(n_base + nt * 16 + c) * 256;
#pragma unroll
        for (int ds = 0; ds < 4; ++ds) {
            u32 lo = pk2(Oacc[nt][ds][0] * inv, Oacc[nt][ds][1] * inv);
            u32 hi = pk2(Oacc[nt][ds][2] * inv, Oacc[nt][ds][3] * inv);
            *(uint2*)(aob + nrow + ds * 16 + g * 4) = make_uint2(lo, hi);
        }
    }
}

// ---------------------------------------------------------------------------
// Kernel 6: proj GEMM, bf16 MFMA, C[o][n], fused bias + fp32 residual.
// ---------------------------------------------------------------------------
__global__ __launch_bounds__(256) void proj_mfma_kernel(
    const u16* __restrict__ Wb, const float* __restrict__ bias,
    const u16* __restrict__ aoT, const float* __restrict__ x,
    float* __restrict__ out)
{
    const int b = blockIdx.z, ot = blockIdx.y, nt = blockIdx.x;
    const int t = threadIdx.x, w = t >> 6, l = t & 63;
    const int g = l >> 4, c = l & 15;
    __shared__ u16 Xlds[64 * 512];
    __shared__ u16 Wlds[32 * 512];
    const u16* Xb = aoT + ((size_t)b * NN + nt * 128) * 256;
    const u16* Wo = Wb + (size_t)ot * 64 * 256;

#pragma unroll
    for (int s = w; s < 64; s += 4) {
        int nsub = s >> 3, ks = s & 7;
        s16x8 v = *(const s16x8*)(Xb + (size_t)(nsub * 16 + c) * 256 + ks * 32 + g * 8);
        *(s16x8*)(Xlds + s * 512 + l * 8) = v;
    }
#pragma unroll
    for (int s = w; s < 32; s += 4) {
        int osub = s >> 3, ks = s & 7;
        s16x8 v = *(const s16x8*)(Wo + (size_t)(osub * 16 + c) * 256 + ks * 32 + g * 8);
        *(s16x8*)(Wlds + s * 512 + l * 8) = v;
    }
    __syncthreads();

    f32x4 acc[8];
#pragma unroll
    for (int j = 0; j < 8; ++j) acc[j] = (f32x4){0.f, 0.f, 0.f, 0.f};
#pragma unroll
    for (int ks = 0; ks < 8; ++ks) {
        s16x8 a = *(const s16x8*)(Wlds + (w * 8 + ks) * 512 + l * 8);
#pragma unroll
        for (int j = 0; j < 8; ++j) {
            s16x8 xf = *(const s16x8*)(Xlds + (j * 8 + ks) * 512 + l * 8);
            acc[j] = __builtin_amdgcn_mfma_f32_16x16x32_bf16(a, xf, acc[j], 0, 0, 0);
        }
    }
    float bv[4];
#pragma unroll
    for (int r = 0; r < 4; ++r) bv[r] = bias[ot * 64 + w * 16 + g * 4 + r];
#pragma unroll
    for (int j = 0; j < 8; ++j)
#pragma unroll
        for (int r = 0; r < 4; ++r) {
            int o = ot * 64 + w * 16 + g * 4 + r;
            int n = nt * 128 + j * 16 + c;
            size_t addr = ((size_t)b * 256 + o) * NN + n;
            out[addr] = acc[j][r] + bv[r] + x[addr];
        }
}

// ---------------------------------------------------------------------------
extern "C" void kernel_launch(void* const* d_in, const int* in_sizes, int n_in,
                              void* d_out, int out_size, void* d_ws, size_t ws_size,
                              hipStream_t stream)
{
    const float* x      = (const float*)d_in[0];
    const float* gamma  = (const float*)d_in[1];
    const float* beta   = (const float*)d_in[2];
    const float* qkv_w  = (const float*)d_in[3];
    const float* qkv_b  = (const float*)d_in[4];
    const float* proj_w = (const float*)d_in[5];
    const float* proj_b = (const float*)d_in[6];
    float* out = (float*)d_out;

    float* ws = (float*)d_ws;
    float2* stats = (float2*)ws;                  // 4 KB
    u16* Xt  = (u16*)(ws + 1024);                 // [B][1024 n][256 c]
    u16* wqb = Xt + (size_t)4194304;              // [768][256]
    u16* wpb = wqb + (size_t)196608;              // [256][256]
    u16* qh  = wpb + (size_t)65536;               // [B*4][1024 n][64 d]
    u16* kh  = qh + (size_t)4194304;              // [B*4][1024 m][64 d]
    u16* vh  = kh + (size_t)4194304;              // [B*4][64 d][1024 m]
    u16* aoT = vh + (size_t)4194304;              // [B][1024 n][256 c]

    gn_stats_kernel<<<dim3(NB * 32), 256, 0, stream>>>(x, stats);
    wcvt_kernel<<<dim3(256), 256, 0, stream>>>(qkv_w, proj_w, wqb, wpb);
    gnorm_t_kernel<<<dim3(16, 4, NB), 256, 0, stream>>>(x, stats, gamma, beta, Xt);

    qkv_mfma_kernel<<<dim3(8, 12, NB), 256, 0, stream>>>(
        wqb, qkv_b, Xt, qh, kh, vh);

    attn_mfma_kernel<<<dim3(512), 256, 0, stream>>>(qh, kh, vh, aoT);

    proj_mfma_kernel<<<dim3(8, 4, NB), 256, 0, stream>>>(
        wpb, proj_b, aoT, x, out);
}

// Round 5
// 89.351 us; speedup vs baseline: 5.4152x; 1.4953x over previous
//
#include <hip/hip_runtime.h>
#include <math.h>

typedef unsigned short u16;
typedef unsigned int u32;
typedef __attribute__((ext_vector_type(8))) short s16x8;
typedef __attribute__((ext_vector_type(4))) float f32x4;

#define NB 16
#define NN 1024
#define GN_EPS 1e-5f

// cheap bf16 round (ties-away): 2 VALU ops
static __device__ __forceinline__ u16 f2bf(float f) {
    union { float f; u32 u; } v; v.f = f;
    return (u16)((v.u + 0x8000u) >> 16);
}
// pack two floats -> two bf16 in one u32: 2 adds + 1 v_perm_b32
static __device__ __forceinline__ u32 pk2(float a, float b) {
    union { float f; u32 u; } A, B; A.f = a; B.f = b;
    return __builtin_amdgcn_perm(A.u + 0x8000u, B.u + 0x8000u, 0x03020706u);
}

// ---------------------------------------------------------------------------
// Kernel 1: GroupNorm statistics. One block per (b, g); 8192 contiguous floats.
// ---------------------------------------------------------------------------
__global__ __launch_bounds__(256) void gn_stats_kernel(
    const float* __restrict__ x, float2* __restrict__ stats)
{
    const int bg = blockIdx.x;
    const int t  = threadIdx.x;
    const size_t base = (size_t)bg * 8192;
    float s = 0.f, ss = 0.f;
#pragma unroll
    for (int i = 0; i < 32; ++i) {
        float v = x[base + t + i * 256];
        s += v; ss += v * v;
    }
#pragma unroll
    for (int off = 32; off > 0; off >>= 1) {
        s  += __shfl_down(s, off);
        ss += __shfl_down(ss, off);
    }
    __shared__ float red[8];
    const int wid = t >> 6;
    if ((t & 63) == 0) { red[wid] = s; red[4 + wid] = ss; }
    __syncthreads();
    if (t == 0) {
        float sa = red[0] + red[1] + red[2] + red[3];
        float sb = red[4] + red[5] + red[6] + red[7];
        float mean = sa * (1.0f / 8192.0f);
        float var  = sb * (1.0f / 8192.0f) - mean * mean;
        stats[bg] = make_float2(mean, 1.0f / sqrtf(var + GN_EPS));
    }
}

// ---------------------------------------------------------------------------
// Kernel 2: weights fp32 -> bf16 (contiguous). 65536 threads x 4 elems.
// ---------------------------------------------------------------------------
__global__ __launch_bounds__(256) void wcvt_kernel(
    const float* __restrict__ qkv_w, const float* __restrict__ proj_w,
    u16* __restrict__ wqb, u16* __restrict__ wpb)
{
    int i = blockIdx.x * 256 + threadIdx.x;   // 0..65535, 4 floats each
    if (i < 49152) {
        float4 f = ((const float4*)qkv_w)[i];
        *(uint2*)(wqb + (size_t)i * 4) = make_uint2(pk2(f.x, f.y), pk2(f.z, f.w));
    } else {
        int j = i - 49152;                    // 0..16383
        float4 f = ((const float4*)proj_w)[j];
        *(uint2*)(wpb + (size_t)j * 4) = make_uint2(pk2(f.x, f.y), pk2(f.z, f.w));
    }
}

// ---------------------------------------------------------------------------
// Kernel 3: GroupNorm-apply + transpose: x[b][c][n] fp32 -> Xt[b][n][c] bf16.
// ---------------------------------------------------------------------------
__global__ __launch_bounds__(256) void gnorm_t_kernel(
    const float* __restrict__ x, const float2* __restrict__ stats,
    const float* __restrict__ gamma, const float* __restrict__ beta,
    u16* __restrict__ Xt)
{
    const int b = blockIdx.z, ct = blockIdx.y, nt = blockIdx.x;
    const int t = threadIdx.x;
    __shared__ float T[64][65];
    const float* xb = x + ((size_t)b * 256 + ct * 64) * NN + nt * 64;
#pragma unroll
    for (int i = 0; i < 16; ++i) {
        int idx = t + i * 256;
        int cr = idx >> 6, col = idx & 63;
        int ch = ct * 64 + cr;
        float2 st = stats[b * 32 + (ch >> 3)];
        float v = xb[(size_t)cr * NN + col];
        T[cr][col] = (v - st.x) * st.y * gamma[ch] + beta[ch];
    }
    __syncthreads();
    u16* dst = Xt + ((size_t)b * NN + nt * 64) * 256 + ct * 64;
#pragma unroll
    for (int p = 0; p < 2; ++p) {
        int idx = t + p * 256;
        int nl = idx >> 3, c8 = idx & 7;
        s16x8 pv;
#pragma unroll
        for (int j = 0; j < 8; ++j) pv[j] = (short)f2bf(T[c8 * 8 + j][nl]);
        *(s16x8*)(dst + (size_t)nl * 256 + c8 * 8) = pv;
    }
}

// ---------------------------------------------------------------------------
// Kernel 4: QKV GEMM, bf16 MFMA. Block: 128n x 64o, K tiled by 128 (2 rounds,
// single LDS buffer: 48 KB -> 3 blocks/CU). q/k swapped-operand -> C[n][d];
// v normal -> C[d][m].
// ---------------------------------------------------------------------------
__global__ __launch_bounds__(256) void qkv_mfma_kernel(
    const u16* __restrict__ Wb, const float* __restrict__ bias,
    const u16* __restrict__ Xt,
    u16* __restrict__ qh, u16* __restrict__ kh, u16* __restrict__ vh)
{
    const int b = blockIdx.z, ot = blockIdx.y, nt = blockIdx.x;
    const int t = threadIdx.x, w = t >> 6, l = t & 63;
    const int g = l >> 4, c = l & 15;
    __shared__ u16 Xlds[32 * 512];   // slot (nsub*4+ks), 32k per slot
    __shared__ u16 Wlds[16 * 512];   // slot (osub*4+ks)
    const u16* Xb = Xt + ((size_t)b * NN + nt * 128) * 256;
    const u16* Wo = Wb + (size_t)ot * 64 * 256;

    const int part = ot >> 2, h = ot & 3;
    const size_t bhoff = (size_t)(b * 4 + h) << 16;

    if (part < 2) {
        f32x4 acc[2][4];
#pragma unroll
        for (int i = 0; i < 2; ++i)
#pragma unroll
            for (int j = 0; j < 4; ++j) acc[i][j] = (f32x4){0.f, 0.f, 0.f, 0.f};
        for (int kk = 0; kk < 256; kk += 128) {
            if (kk) __syncthreads();
#pragma unroll
            for (int s = w; s < 32; s += 4) {
                int nsub = s >> 2, ks = s & 3;
                s16x8 v = *(const s16x8*)(Xb + (size_t)(nsub * 16 + c) * 256 + kk + ks * 32 + g * 8);
                *(s16x8*)(Xlds + s * 512 + l * 8) = v;
            }
#pragma unroll
            for (int s = w; s < 16; s += 4) {
                int osub = s >> 2, ks = s & 3;
                s16x8 v = *(const s16x8*)(Wo + (size_t)(osub * 16 + c) * 256 + kk + ks * 32 + g * 8);
                *(s16x8*)(Wlds + s * 512 + l * 8) = v;
            }
            __syncthreads();
#pragma unroll
            for (int ks = 0; ks < 4; ++ks) {
                s16x8 a0 = *(const s16x8*)(Xlds + ((2 * w) * 4 + ks) * 512 + l * 8);
                s16x8 a1 = *(const s16x8*)(Xlds + ((2 * w + 1) * 4 + ks) * 512 + l * 8);
#pragma unroll
                for (int j = 0; j < 4; ++j) {
                    s16x8 bf = *(const s16x8*)(Wlds + (j * 4 + ks) * 512 + l * 8);
                    acc[0][j] = __builtin_amdgcn_mfma_f32_16x16x32_bf16(a0, bf, acc[0][j], 0, 0, 0);
                    acc[1][j] = __builtin_amdgcn_mfma_f32_16x16x32_bf16(a1, bf, acc[1][j], 0, 0, 0);
                }
            }
        }
        const float sc = (part == 0) ? 0.125f : 1.0f;
        float bv[4];
#pragma unroll
        for (int j = 0; j < 4; ++j) bv[j] = bias[ot * 64 + j * 16 + c];
        u16* dst = (part == 0 ? qh : kh) + bhoff + (size_t)(nt * 128) * 64;
#pragma unroll
        for (int i = 0; i < 2; ++i)
#pragma unroll
            for (int j = 0; j < 4; ++j)
#pragma unroll
                for (int r = 0; r < 4; ++r) {
                    int n = (2 * w + i) * 16 + g * 4 + r;
                    dst[(size_t)n * 64 + j * 16 + c] = f2bf((acc[i][j][r] + bv[j]) * sc);
                }
    } else {
        f32x4 acc[8];
#pragma unroll
        for (int j = 0; j < 8; ++j) acc[j] = (f32x4){0.f, 0.f, 0.f, 0.f};
        for (int kk = 0; kk < 256; kk += 128) {
            if (kk) __syncthreads();
#pragma unroll
            for (int s = w; s < 32; s += 4) {
                int nsub = s >> 2, ks = s & 3;
                s16x8 v = *(const s16x8*)(Xb + (size_t)(nsub * 16 + c) * 256 + kk + ks * 32 + g * 8);
                *(s16x8*)(Xlds + s * 512 + l * 8) = v;
            }
#pragma unroll
            for (int s = w; s < 16; s += 4) {
                int osub = s >> 2, ks = s & 3;
                s16x8 v = *(const s16x8*)(Wo + (size_t)(osub * 16 + c) * 256 + kk + ks * 32 + g * 8);
                *(s16x8*)(Wlds + s * 512 + l * 8) = v;
            }
            __syncthreads();
#pragma unroll
            for (int ks = 0; ks < 4; ++ks) {
                s16x8 a = *(const s16x8*)(Wlds + (w * 4 + ks) * 512 + l * 8);
#pragma unroll
                for (int j = 0; j < 8; ++j) {
                    s16x8 xf = *(const s16x8*)(Xlds + (j * 4 + ks) * 512 + l * 8);
                    acc[j] = __builtin_amdgcn_mfma_f32_16x16x32_bf16(a, xf, acc[j], 0, 0, 0);
                }
            }
        }
        float bv[4];
#pragma unroll
        for (int r = 0; r < 4; ++r) bv[r] = bias[ot * 64 + w * 16 + g * 4 + r];
        u16* dst = vh + bhoff;
#pragma unroll
        for (int j = 0; j < 8; ++j)
#pragma unroll
            for (int r = 0; r < 4; ++r) {
                int d = w * 16 + g * 4 + r;
                int m = nt * 128 + j * 16 + c;
                dst[(size_t)d * NN + m] = f2bf(acc[j][r] + bv[r]);
            }
    }
}

// ---------------------------------------------------------------------------
// Kernel 5: MFMA flash attention. 512 threads / 8 waves, 16 queries per wave,
// 128 queries per block. Grid 512, XCD-swizzled. Defer-max THR=8.
// LDS: K 8KB + V 8KB + P 16KB = 32KB.
// ---------------------------------------------------------------------------
__global__ __launch_bounds__(512) void attn_mfma_kernel(
    const u16* __restrict__ qh, const u16* __restrict__ kh,
    const u16* __restrict__ vh, u16* __restrict__ aoT)
{
    const int t = threadIdx.x;
    const int w = t >> 6, l = t & 63;
    const int g = l >> 4, c = l & 15;
    // swizzle: bid = xcd + 8*(qt + 8*gi); group = gi*8 + xcd
    const int bid = blockIdx.x;
    const int xcd = bid & 7;
    const int idx = bid >> 3;
    const int qt  = idx & 7;
    const int grp = (idx >> 3) * 8 + xcd;     // 0..63
    const int b = grp >> 2, h = grp & 3;
    const size_t bhoff = (size_t)grp << 16;
    const int n_base = qt * 128 + w * 16;

    __shared__ u16 Klds[8 * 512];
    __shared__ u16 Vlds[8 * 512];
    __shared__ u16 Plds[8][2 * 512];

    const u16* qb = qh + bhoff;
    const u16* kb = kh + bhoff;
    const u16* vb = vh + bhoff;

    s16x8 qf[2];
#pragma unroll
    for (int u = 0; u < 2; ++u)
        qf[u] = *(const s16x8*)(qb + (size_t)(n_base + c) * 64 + u * 32 + g * 8);

    f32x4 Oacc[4];
    float m_run = -1e30f, l_run = 0.f;
#pragma unroll
    for (int ds = 0; ds < 4; ++ds) Oacc[ds] = (f32x4){0.f, 0.f, 0.f, 0.f};

    u16* pw = &Plds[w][0];

    for (int mt = 0; mt < 16; ++mt) {
        const int m0 = mt * 64;
        __syncthreads();
        {   // stage K slot w: k[m0 + msub*16 + c][u*32 + g*8 ..+8]
            int msub = w >> 1, u = w & 1;
            s16x8 kv = *(const s16x8*)(kb + (size_t)(m0 + msub * 16 + c) * 64 + u * 32 + g * 8);
            *(s16x8*)(Klds + w * 512 + l * 8) = kv;
        }
        {   // stage V slot w: v[dsub*16 + c][m0 + u*32 + g*8 ..+8]
            int dsub = w >> 1, u = w & 1;
            s16x8 vv = *(const s16x8*)(vb + (size_t)(dsub * 16 + c) * NN + m0 + u * 32 + g * 8);
            *(s16x8*)(Vlds + w * 512 + l * 8) = vv;
        }
        __syncthreads();

        // QK^T: S^T[m][n], C row = g*4+r (m), col = c (n)
        f32x4 S[4];
#pragma unroll
        for (int ms = 0; ms < 4; ++ms) S[ms] = (f32x4){0.f, 0.f, 0.f, 0.f};
#pragma unroll
        for (int ms = 0; ms < 4; ++ms)
#pragma unroll
            for (int u = 0; u < 2; ++u) {
                s16x8 af = *(const s16x8*)(Klds + (ms * 2 + u) * 512 + l * 8);
                S[ms] = __builtin_amdgcn_mfma_f32_16x16x32_bf16(af, qf[u], S[ms], 0, 0, 0);
            }

        s16x8 vf[4][2];
#pragma unroll
        for (int ds = 0; ds < 4; ++ds)
#pragma unroll
            for (int u = 0; u < 2; ++u)
                vf[ds][u] = *(const s16x8*)(Vlds + (ds * 2 + u) * 512 + l * 8);

        float tmax = -1e30f;
#pragma unroll
        for (int ms = 0; ms < 4; ++ms)
#pragma unroll
            for (int r = 0; r < 4; ++r) tmax = fmaxf(tmax, S[ms][r]);
        tmax = fmaxf(tmax, __shfl_xor(tmax, 16));
        tmax = fmaxf(tmax, __shfl_xor(tmax, 32));
        // defer-max: rescale only if some column grew by > 8
        if (!__all(tmax <= m_run + 8.f)) {
            float nm  = fmaxf(m_run, tmax);
            float fac = __expf(m_run - nm);
            m_run = nm;
            l_run *= fac;
#pragma unroll
            for (int ds = 0; ds < 4; ++ds)
#pragma unroll
                for (int r = 0; r < 4; ++r) Oacc[ds][r] *= fac;
        }
        const float mm = m_run;
        float rsum = 0.f;
#pragma unroll
        for (int ms = 0; ms < 4; ++ms)
#pragma unroll
            for (int r = 0; r < 4; ++r) {
                float p = __expf(S[ms][r] - mm);
                S[ms][r] = p;
                rsum += p;
            }
        rsum += __shfl_xor(rsum, 16);
        rsum += __shfl_xor(rsum, 32);
        l_run += rsum;
        // P store (wave-private): m = ms*16+g*4+r -> slot ms>>1
#pragma unroll
        for (int ms = 0; ms < 4; ++ms) {
            u32 d0 = pk2(S[ms][0], S[ms][1]);
            u32 d1 = pk2(S[ms][2], S[ms][3]);
            int off = (ms >> 1) * 512 + ((ms & 1) * 2 + (g >> 1)) * 128 + c * 8 + (g & 1) * 4;
            *(uint2*)(pw + off) = make_uint2(d0, d1);
        }
        asm volatile("s_waitcnt lgkmcnt(0)" ::: "memory");
#pragma unroll
        for (int u = 0; u < 2; ++u) {
            s16x8 pf = *(const s16x8*)(pw + u * 512 + l * 8);
#pragma unroll
            for (int ds = 0; ds < 4; ++ds)
                Oacc[ds] = __builtin_amdgcn_mfma_f32_16x16x32_bf16(vf[ds][u], pf, Oacc[ds], 0, 0, 0);
        }
    }

    // write aoT[b][n][h*64 + d] bf16
    u16* aob = aoT + (size_t)b * NN * 256 + h * 64;
    float inv = 1.0f / l_run;
    const size_t nrow = (size_t)(n_base + c) * 256;
#pragma unroll
    for (int ds = 0; ds < 4; ++ds) {
        u32 lo = pk2(Oacc[ds][0] * inv, Oacc[ds][1] * inv);
        u32 hi = pk2(Oacc[ds][2] * inv, Oacc[ds][3] * inv);
        *(uint2*)(aob + nrow + ds * 16 + g * 4) = make_uint2(lo, hi);
    }
}

// ---------------------------------------------------------------------------
// Kernel 6: proj GEMM, bf16 MFMA, K tiled by 128 (48 KB LDS), C[o][n],
// fused bias + fp32 residual.
// ---------------------------------------------------------------------------
__global__ __launch_bounds__(256) void proj_mfma_kernel(
    const u16* __restrict__ Wb, const float* __restrict__ bias,
    const u16* __restrict__ aoT, const float* __restrict__ x,
    float* __restrict__ out)
{
    const int b = blockIdx.z, ot = blockIdx.y, nt = blockIdx.x;
    const int t = threadIdx.x, w = t >> 6, l = t & 63;
    const int g = l >> 4, c = l & 15;
    __shared__ u16 Xlds[32 * 512];
    __shared__ u16 Wlds[16 * 512];
    const u16* Xb = aoT + ((size_t)b * NN + nt * 128) * 256;
    const u16* Wo = Wb + (size_t)ot * 64 * 256;

    f32x4 acc[8];
#pragma unroll
    for (int j = 0; j < 8; ++j) acc[j] = (f32x4){0.f, 0.f, 0.f, 0.f};
    for (int kk = 0; kk < 256; kk += 128) {
        if (kk) __syncthreads();
#pragma unroll
        for (int s = w; s < 32; s += 4) {
            int nsub = s >> 2, ks = s & 3;
            s16x8 v = *(const s16x8*)(Xb + (size_t)(nsub * 16 + c) * 256 + kk + ks * 32 + g * 8);
            *(s16x8*)(Xlds + s * 512 + l * 8) = v;
        }
#pragma unroll
        for (int s = w; s < 16; s += 4) {
            int osub = s >> 2, ks = s & 3;
            s16x8 v = *(const s16x8*)(Wo + (size_t)(osub * 16 + c) * 256 + kk + ks * 32 + g * 8);
            *(s16x8*)(Wlds + s * 512 + l * 8) = v;
        }
        __syncthreads();
#pragma unroll
        for (int ks = 0; ks < 4; ++ks) {
            s16x8 a = *(const s16x8*)(Wlds + (w * 4 + ks) * 512 + l * 8);
#pragma unroll
            for (int j = 0; j < 8; ++j) {
                s16x8 xf = *(const s16x8*)(Xlds + (j * 4 + ks) * 512 + l * 8);
                acc[j] = __builtin_amdgcn_mfma_f32_16x16x32_bf16(a, xf, acc[j], 0, 0, 0);
            }
        }
    }
    float bv[4];
#pragma unroll
    for (int r = 0; r < 4; ++r) bv[r] = bias[ot * 64 + w * 16 + g * 4 + r];
#pragma unroll
    for (int j = 0; j < 8; ++j)
#pragma unroll
        for (int r = 0; r < 4; ++r) {
            int o = ot * 64 + w * 16 + g * 4 + r;
            int n = nt * 128 + j * 16 + c;
            size_t addr = ((size_t)b * 256 + o) * NN + n;
            out[addr] = acc[j][r] + bv[r] + x[addr];
        }
}

// ---------------------------------------------------------------------------
extern "C" void kernel_launch(void* const* d_in, const int* in_sizes, int n_in,
                              void* d_out, int out_size, void* d_ws, size_t ws_size,
                              hipStream_t stream)
{
    const float* x      = (const float*)d_in[0];
    const float* gamma  = (const float*)d_in[1];
    const float* beta   = (const float*)d_in[2];
    const float* qkv_w  = (const float*)d_in[3];
    const float* qkv_b  = (const float*)d_in[4];
    const float* proj_w = (const float*)d_in[5];
    const float* proj_b = (const float*)d_in[6];
    float* out = (float*)d_out;

    float* ws = (float*)d_ws;
    float2* stats = (float2*)ws;                  // 4 KB
    u16* Xt  = (u16*)(ws + 1024);                 // [B][1024 n][256 c]
    u16* wqb = Xt + (size_t)4194304;              // [768][256]
    u16* wpb = wqb + (size_t)196608;              // [256][256]
    u16* qh  = wpb + (size_t)65536;               // [B*4][1024 n][64 d]
    u16* kh  = qh + (size_t)4194304;              // [B*4][1024 m][64 d]
    u16* vh  = kh + (size_t)4194304;              // [B*4][64 d][1024 m]
    u16* aoT = vh + (size_t)4194304;              // [B][1024 n][256 c]

    gn_stats_kernel<<<dim3(NB * 32), 256, 0, stream>>>(x, stats);
    wcvt_kernel<<<dim3(256), 256, 0, stream>>>(qkv_w, proj_w, wqb, wpb);
    gnorm_t_kernel<<<dim3(16, 4, NB), 256, 0, stream>>>(x, stats, gamma, beta, Xt);

    qkv_mfma_kernel<<<dim3(8, 12, NB), 256, 0, stream>>>(
        wqb, qkv_b, Xt, qh, kh, vh);

    attn_mfma_kernel<<<dim3(512), 512, 0, stream>>>(qh, kh, vh, aoT);

    proj_mfma_kernel<<<dim3(8, 4, NB), 256, 0, stream>>>(
        wpb, proj_b, aoT, x, out);
}